// Round 19
// baseline (214.647 us; speedup 1.0000x reference)
//
#include <hip/hip_runtime.h>

#define CH 128
#define MM 64
#define BB 128
#define NN 4096
#define KSPLIT 8
#define KCHUNK (NN / KSPLIT)   // 512
#define KSTEP 32
#define NSTEP (KCHUNK / KSTEP) // 16

#define UBUF (KSTEP * MM)      // 2048 floats = 8 KB
#define HBUF (KSTEP * CH)      // 4096 floats = 16 KB
#define BUF  (UBUF + HBUF)     // 6144 floats = 24 KB
#define MMCH (MM * CH)

typedef __bf16 bf16x8 __attribute__((ext_vector_type(8)));
typedef float  f32x4  __attribute__((ext_vector_type(4)));

#define AS1(p) ((const __attribute__((address_space(1))) void*)(p))
#define AS3(p) ((__attribute__((address_space(3))) void*)(p))

__device__ __forceinline__ void gl_lds16(const float* g, float* l) {
    __builtin_amdgcn_global_load_lds(AS1(g), AS3(l), 16, 0, 0);
}

// ---------------------------------------------------------------------------
// Kernel 1 — R17-diag-validated config as real work: 1024 blocks (KSPLIT=8),
// 3 LDS buffers (72 KB), depth-2 prefetch, vmcnt(12/6/0). That exact shape
// measured ~105 us/pass (R17). Compute/remap identical (HW-validated R10).
// ---------------------------------------------------------------------------
__global__ __launch_bounds__(256, 2) void k1_uth(const float* __restrict__ U,
                                                 const float* __restrict__ h,
                                                 float* __restrict__ hhp) {
    __shared__ float lds[3 * BUF];     // 72 KB

    const int tid  = threadIdx.x;
    const int lane = tid & 63;
    const int wv   = tid >> 6;          // 0..3 -> c-tiles {2wv, 2wv+1}
    const int b    = blockIdx.x >> 3;   // KSPLIT = 8
    const int ks   = blockIdx.x & 7;
    const int k0   = ks * KCHUNK;

    const int l15 = lane & 15;
    const int g   = lane >> 4;
    const int lk  = g * 8;              // k-offset within 32

    const float* Ub = U + ((size_t)b * NN + k0) * MM;
    const float* hb = h + ((size_t)b * NN + k0) * CH;

    auto stage = [&](int s, int t) {    // 6 gl_lds16 per thread
        float* dst = &lds[s * BUF];
        const float* us = Ub + (size_t)t * KSTEP * MM;
        const float* hs = hb + (size_t)t * KSTEP * CH;
        gl_lds16(us + tid * 4,        dst + tid * 4);
        gl_lds16(us + 1024 + tid * 4, dst + 1024 + tid * 4);
        gl_lds16(hs + tid * 4,        dst + UBUF + tid * 4);
        gl_lds16(hs + 1024 + tid * 4, dst + UBUF + 1024 + tid * 4);
        gl_lds16(hs + 2048 + tid * 4, dst + UBUF + 2048 + tid * 4);
        gl_lds16(hs + 3072 + tid * 4, dst + UBUF + 3072 + tid * 4);
    };

    f32x4 acc[4][2];
    #pragma unroll
    for (int t = 0; t < 4; ++t)
        #pragma unroll
        for (int ci = 0; ci < 2; ++ci)
            acc[t][ci] = (f32x4){0.f, 0.f, 0.f, 0.f};

    auto compute = [&](int s) {
        const float* P  = &lds[s * BUF];
        const float* Pa = P + lk * 64 + 2 * l15;
        const float* Pb = P + UBUF + lk * 128 + wv * 32 + 2 * l15;
        bf16x8 af[4], bfr[2];
        #pragma unroll
        for (int j = 0; j < 8; ++j) {
            float2 a0 = *(const float2*)(Pa + j * 64);
            float2 a1 = *(const float2*)(Pa + j * 64 + 32);
            float2 bv = *(const float2*)(Pb + j * 128);
            af[0][j]  = (__bf16)a0.x;   // m = 2r
            af[1][j]  = (__bf16)a0.y;   // m = 2r+1
            af[2][j]  = (__bf16)a1.x;   // m = 32+2r
            af[3][j]  = (__bf16)a1.y;   // m = 33+2r
            bfr[0][j] = (__bf16)bv.x;   // c = wv*32+2c
            bfr[1][j] = (__bf16)bv.y;   // c = wv*32+2c+1
        }
        #pragma unroll
        for (int t = 0; t < 4; ++t)
            #pragma unroll
            for (int ci = 0; ci < 2; ++ci)
                acc[t][ci] = __builtin_amdgcn_mfma_f32_16x16x32_bf16(
                    af[t], bfr[ci], acc[t][ci], 0, 0, 0);
    };

    stage(0, 0);
    stage(1, 1);
    #pragma unroll 1
    for (int t = 0; t < NSTEP; ++t) {
        if (t + 2 < NSTEP) {
            stage((t + 2) % 3, t + 2);                      // depth-2 prefetch
            asm volatile("s_waitcnt vmcnt(12)" ::: "memory");
        } else if (t + 1 < NSTEP) {
            asm volatile("s_waitcnt vmcnt(6)" ::: "memory");
        } else {
            asm volatile("s_waitcnt vmcnt(0)" ::: "memory");
        }
        __builtin_amdgcn_s_barrier();
        __builtin_amdgcn_sched_barrier(0);
        compute(t % 3);
        __builtin_amdgcn_s_barrier();
    }

    // store: D[row=g*4+r][col=l15]; m = (t>>1)*32 + 2*(g*4+r) + (t&1);
    // c = wv*32 + 2*l15 + ci -> ci pair merges into one float2.
    float* dst = hhp + (size_t)(b * KSPLIT + ks) * MMCH + wv * 32 + 2 * l15;
    #pragma unroll
    for (int t = 0; t < 4; ++t)
        #pragma unroll
        for (int r = 0; r < 4; ++r) {
            const int m = (t >> 1) * 32 + 2 * (g * 4 + r) + (t & 1);
            *(float2*)(dst + (size_t)m * CH) =
                make_float2(acc[t][0][r], acc[t][1][r]);
        }
}

// ---------------------------------------------------------------------------
// Kernel 2 (R8 KSPLIT=8 version): oh[b][m][o] = sum_c (sum_ks partial) *
// W[m][c][o], stored bf16 in MFMA B-fragment order. grid: (MM, BB/16), 256 thr.
// ---------------------------------------------------------------------------
__global__ __launch_bounds__(256) void k2_mix(const float* __restrict__ hhp,
                                              const float* __restrict__ W,
                                              __bf16* __restrict__ ohf) {
    __shared__ float hs[16][CH];
    const int tid  = threadIdx.x;
    const int o    = tid & 127;
    const int half = tid >> 7;
    const int m    = blockIdx.x;
    const int b0   = blockIdx.y * 16;

    #pragma unroll
    for (int i = 0; i < 8; ++i) {
        const int b = b0 + half * 8 + i;
        const float* src = hhp + ((size_t)(b * KSPLIT) * MM + m) * CH + o;
        float s = 0.f;
        #pragma unroll
        for (int ksi = 0; ksi < KSPLIT; ++ksi)
            s += src[(size_t)ksi * MMCH];
        hs[half * 8 + i][o] = s;
    }
    __syncthreads();

    float acc[8];
    #pragma unroll
    for (int i = 0; i < 8; ++i) acc[i] = 0.f;

    const float* Wm = W + (size_t)m * CH * CH;
    for (int c = 0; c < CH; ++c) {
        const float w = Wm[c * CH + o];
        #pragma unroll
        for (int i = 0; i < 8; ++i) acc[i] += hs[half * 8 + i][c] * w;
    }

    const int mt      = m >> 5;
    const int m5      = m & 31;
    const int lane_hi = m5 >> 3;
    const int j       = m5 & 7;
    const int ot      = o >> 4;
    const int lane    = lane_hi * 16 + (o & 15);
    const size_t eidx = ((size_t)(mt * 8 + ot) * 64 + lane) * 8 + j;

    #pragma unroll
    for (int i = 0; i < 8; ++i) {
        const int b = b0 + half * 8 + i;
        ohf[(size_t)b * 8192 + eidx] = (__bf16)acc[i];
    }
}

// ---------------------------------------------------------------------------
// Kernel 3 (unchanged): out[b][n][o] = sum_m U[b][n][m]*oh[b][m][o], MFMA.
// grid: (NN/64, BB), 256 threads = 4 waves, wave = 16 n-rows.
// ---------------------------------------------------------------------------
__global__ __launch_bounds__(256) void k3_back(const float* __restrict__ U,
                                               const __bf16* __restrict__ ohf,
                                               float* __restrict__ out) {
    const int tid  = threadIdx.x;
    const int lane = tid & 63;
    const int wv   = tid >> 6;
    const int n0   = blockIdx.x * 64;
    const int b    = blockIdx.y;

    const bf16x8* ohfb = (const bf16x8*)(ohf + (size_t)b * 8192);
    bf16x8 bf[2][8];
    #pragma unroll
    for (int mt = 0; mt < 2; ++mt)
        #pragma unroll
        for (int ot = 0; ot < 8; ++ot)
            bf[mt][ot] = ohfb[(mt * 8 + ot) * 64 + lane];

    const float* arow = U + ((size_t)b * NN + n0 + wv * 16 + (lane & 15)) * MM
                          + ((lane >> 4) << 3);
    bf16x8 af[2];
    #pragma unroll
    for (int mt = 0; mt < 2; ++mt) {
        float4 a0 = *(const float4*)(arow + mt * 32);
        float4 a1 = *(const float4*)(arow + mt * 32 + 4);
        af[mt][0] = (__bf16)a0.x; af[mt][1] = (__bf16)a0.y;
        af[mt][2] = (__bf16)a0.z; af[mt][3] = (__bf16)a0.w;
        af[mt][4] = (__bf16)a1.x; af[mt][5] = (__bf16)a1.y;
        af[mt][6] = (__bf16)a1.z; af[mt][7] = (__bf16)a1.w;
    }

    f32x4 acc[8];
    #pragma unroll
    for (int ot = 0; ot < 8; ++ot) acc[ot] = (f32x4){0.f, 0.f, 0.f, 0.f};

    #pragma unroll
    for (int ot = 0; ot < 8; ++ot) {
        acc[ot] = __builtin_amdgcn_mfma_f32_16x16x32_bf16(af[0], bf[0][ot], acc[ot], 0, 0, 0);
        acc[ot] = __builtin_amdgcn_mfma_f32_16x16x32_bf16(af[1], bf[1][ot], acc[ot], 0, 0, 0);
    }

    float* dst = out + ((size_t)b * NN + n0 + wv * 16 + (lane >> 4) * 4) * CH + (lane & 15);
    #pragma unroll
    for (int ot = 0; ot < 8; ++ot)
        #pragma unroll
        for (int r = 0; r < 4; ++r)
            dst[(size_t)r * CH + ot * 16] = acc[ot][r];
}

// ---------------------------------------------------------------------------
extern "C" void kernel_launch(void* const* d_in, const int* in_sizes, int n_in,
                              void* d_out, int out_size, void* d_ws, size_t ws_size,
                              hipStream_t stream) {
    const float* h = (const float*)d_in[0];   // [B*N, C]
    const float* U = (const float*)d_in[1];   // [B, N, M]
    const float* W = (const float*)d_in[2];   // [M, C, C]
    float* out = (float*)d_out;

    float*  hhp = (float*)d_out;              // [B*KSPLIT, M, C] partials (34 MB)
    __bf16* ohf = (__bf16*)d_ws;              // [B, 8192] bf16 B-fragments (2 MB)

    k1_uth<<<BB * KSPLIT, 256, 0, stream>>>(U, h, hhp);
    k2_mix<<<dim3(MM, BB / 16), 256, 0, stream>>>(hhp, W, ohf);
    k3_back<<<dim3(NN / 64, BB), 256, 0, stream>>>(U, ohf, out);
}

// Round 20
// 194.415 us; speedup vs baseline: 1.1041x; 1.1041x over previous
//
#include <hip/hip_runtime.h>

#define CH 128
#define MM 64
#define BB 128
#define NN 4096
#define NC 4
#define CB (BB / NC)           // 32 batches per chunk
#define KSPLIT 4
#define KCHUNK (NN / KSPLIT)   // 1024
#define KSTEP 32
#define NSTEP (KCHUNK / KSTEP) // 32

#define UBUF (KSTEP * MM)      // 2048 floats
#define HBUF (KSTEP * CH)      // 4096 floats
#define BUF  (UBUF + HBUF)     // 6144 floats = 24 KB
#define MMCH (MM * CH)

#define N1C (CB * KSPLIT)      // 128 k1-blocks per chunk
#define N2C (64 * (CB / 16))   // 128 k2-blocks per chunk
#define N3C (64 * CB)          // 2048 k3-blocks per chunk

typedef __bf16 bf16x8 __attribute__((ext_vector_type(8)));
typedef float  f32x4  __attribute__((ext_vector_type(4)));

#define AS1(p) ((const __attribute__((address_space(1))) void*)(p))
#define AS3(p) ((__attribute__((address_space(3))) void*)(p))

__device__ __forceinline__ void gl_lds16(const float* g, float* l) {
    __builtin_amdgcn_global_load_lds(AS1(g), AS3(l), 16, 0, 0);
}

// ---------------------------------------------------------------------------
// k1 body — R18 exact (48 KB, 2-buffer, depth-1, vmcnt(6/0)), chunked.
// ---------------------------------------------------------------------------
__device__ __forceinline__ void k1_body(float* lds, const float* __restrict__ U,
                                        const float* __restrict__ h,
                                        float* __restrict__ hhp, int bid, int c1) {
    const int tid  = threadIdx.x;
    const int lane = tid & 63;
    const int wv   = tid >> 6;
    const int b    = c1 * CB + (bid >> 2);
    const int ks   = bid & 3;
    const int k0   = ks * KCHUNK;

    const int l15 = lane & 15;
    const int g   = lane >> 4;
    const int lk  = g * 8;

    const float* Ub = U + ((size_t)b * NN + k0) * MM;
    const float* hb = h + ((size_t)b * NN + k0) * CH;

    auto stage = [&](int s, int t) {
        float* dst = &lds[s * BUF];
        const float* us = Ub + (size_t)t * KSTEP * MM;
        const float* hs = hb + (size_t)t * KSTEP * CH;
        gl_lds16(us + tid * 4,        dst + tid * 4);
        gl_lds16(us + 1024 + tid * 4, dst + 1024 + tid * 4);
        gl_lds16(hs + tid * 4,        dst + UBUF + tid * 4);
        gl_lds16(hs + 1024 + tid * 4, dst + UBUF + 1024 + tid * 4);
        gl_lds16(hs + 2048 + tid * 4, dst + UBUF + 2048 + tid * 4);
        gl_lds16(hs + 3072 + tid * 4, dst + UBUF + 3072 + tid * 4);
    };

    f32x4 acc[4][2];
    #pragma unroll
    for (int t = 0; t < 4; ++t)
        #pragma unroll
        for (int ci = 0; ci < 2; ++ci)
            acc[t][ci] = (f32x4){0.f, 0.f, 0.f, 0.f};

    auto compute = [&](int s) {
        const float* P  = &lds[s * BUF];
        const float* Pa = P + lk * 64 + 2 * l15;
        const float* Pb = P + UBUF + lk * 128 + wv * 32 + 2 * l15;
        bf16x8 af[4], bfr[2];
        #pragma unroll
        for (int j = 0; j < 8; ++j) {
            float2 a0 = *(const float2*)(Pa + j * 64);
            float2 a1 = *(const float2*)(Pa + j * 64 + 32);
            float2 bv = *(const float2*)(Pb + j * 128);
            af[0][j]  = (__bf16)a0.x;
            af[1][j]  = (__bf16)a0.y;
            af[2][j]  = (__bf16)a1.x;
            af[3][j]  = (__bf16)a1.y;
            bfr[0][j] = (__bf16)bv.x;
            bfr[1][j] = (__bf16)bv.y;
        }
        #pragma unroll
        for (int t = 0; t < 4; ++t)
            #pragma unroll
            for (int ci = 0; ci < 2; ++ci)
                acc[t][ci] = __builtin_amdgcn_mfma_f32_16x16x32_bf16(
                    af[t], bfr[ci], acc[t][ci], 0, 0, 0);
    };

    stage(0, 0);
    #pragma unroll 1
    for (int t = 0; t < NSTEP; ++t) {
        if (t + 1 < NSTEP) {
            stage((t + 1) & 1, t + 1);
            asm volatile("s_waitcnt vmcnt(6)" ::: "memory");
        } else {
            asm volatile("s_waitcnt vmcnt(0)" ::: "memory");
        }
        __builtin_amdgcn_s_barrier();
        __builtin_amdgcn_sched_barrier(0);
        compute(t & 1);
        __builtin_amdgcn_s_barrier();
    }

    float* dst = hhp + (size_t)(b * KSPLIT + ks) * MMCH + wv * 32 + 2 * l15;
    #pragma unroll
    for (int t = 0; t < 4; ++t)
        #pragma unroll
        for (int r = 0; r < 4; ++r) {
            const int m = (t >> 1) * 32 + 2 * (g * 4 + r) + (t & 1);
            *(float2*)(dst + (size_t)m * CH) =
                make_float2(acc[t][0][r], acc[t][1][r]);
        }
}

// ---------------------------------------------------------------------------
// k2 body — R18 exact, chunked (16 b per block; CB=32 -> 2 blocks per m).
// ---------------------------------------------------------------------------
__device__ __forceinline__ void k2_body(float* lds, const float* __restrict__ hhp,
                                        const float* __restrict__ W,
                                        __bf16* __restrict__ ohf, int bid, int c2) {
    float (*hs)[CH] = (float(*)[CH])lds;
    const int tid  = threadIdx.x;
    const int o    = tid & 127;
    const int half = tid >> 7;
    const int m    = bid & 63;
    const int b0   = c2 * CB + (bid >> 6) * 16;

    #pragma unroll
    for (int i = 0; i < 8; ++i) {
        const int b = b0 + half * 8 + i;
        const float* src = hhp + ((size_t)(b * KSPLIT) * MM + m) * CH + o;
        float s = 0.f;
        #pragma unroll
        for (int ksi = 0; ksi < KSPLIT; ++ksi)
            s += src[(size_t)ksi * MMCH];
        hs[half * 8 + i][o] = s;
    }
    __syncthreads();

    float acc[8];
    #pragma unroll
    for (int i = 0; i < 8; ++i) acc[i] = 0.f;

    const float* Wm = W + (size_t)m * CH * CH;
    for (int c = 0; c < CH; ++c) {
        const float w = Wm[c * CH + o];
        #pragma unroll
        for (int i = 0; i < 8; ++i) acc[i] += hs[half * 8 + i][c] * w;
    }

    const int mt      = m >> 5;
    const int m5      = m & 31;
    const int lane_hi = m5 >> 3;
    const int j       = m5 & 7;
    const int ot      = o >> 4;
    const int lane    = lane_hi * 16 + (o & 15);
    const size_t eidx = ((size_t)(mt * 8 + ot) * 64 + lane) * 8 + j;

    #pragma unroll
    for (int i = 0; i < 8; ++i) {
        const int b = b0 + half * 8 + i;
        ohf[(size_t)b * 8192 + eidx] = (__bf16)acc[i];
    }
}

// ---------------------------------------------------------------------------
// k3 body — R18 exact, chunked.
// ---------------------------------------------------------------------------
__device__ __forceinline__ void k3_body(const float* __restrict__ U,
                                        const __bf16* __restrict__ ohf,
                                        float* __restrict__ out, int bid, int c3) {
    const int tid  = threadIdx.x;
    const int lane = tid & 63;
    const int wv   = tid >> 6;
    const int n0   = (bid & 63) * 64;
    const int b    = c3 * CB + (bid >> 6);

    const bf16x8* ohfb = (const bf16x8*)(ohf + (size_t)b * 8192);
    bf16x8 bf[2][8];
    #pragma unroll
    for (int mt = 0; mt < 2; ++mt)
        #pragma unroll
        for (int ot = 0; ot < 8; ++ot)
            bf[mt][ot] = ohfb[(mt * 8 + ot) * 64 + lane];

    const float* arow = U + ((size_t)b * NN + n0 + wv * 16 + (lane & 15)) * MM
                          + ((lane >> 4) << 3);
    bf16x8 af[2];
    #pragma unroll
    for (int mt = 0; mt < 2; ++mt) {
        float4 a0 = *(const float4*)(arow + mt * 32);
        float4 a1 = *(const float4*)(arow + mt * 32 + 4);
        af[mt][0] = (__bf16)a0.x; af[mt][1] = (__bf16)a0.y;
        af[mt][2] = (__bf16)a0.z; af[mt][3] = (__bf16)a0.w;
        af[mt][4] = (__bf16)a1.x; af[mt][5] = (__bf16)a1.y;
        af[mt][6] = (__bf16)a1.z; af[mt][7] = (__bf16)a1.w;
    }

    f32x4 acc[8];
    #pragma unroll
    for (int ot = 0; ot < 8; ++ot) acc[ot] = (f32x4){0.f, 0.f, 0.f, 0.f};

    #pragma unroll
    for (int ot = 0; ot < 8; ++ot) {
        acc[ot] = __builtin_amdgcn_mfma_f32_16x16x32_bf16(af[0], bf[0][ot], acc[ot], 0, 0, 0);
        acc[ot] = __builtin_amdgcn_mfma_f32_16x16x32_bf16(af[1], bf[1][ot], acc[ot], 0, 0, 0);
    }

    float* dst = out + ((size_t)b * NN + n0 + wv * 16 + (lane >> 4) * 4) * CH + (lane & 15);
    #pragma unroll
    for (int ot = 0; ot < 8; ++ot)
        #pragma unroll
        for (int r = 0; r < 4; ++r)
            dst[(size_t)r * CH + ot * 16] = acc[ot][r];
}

// ---------------------------------------------------------------------------
// Heterogeneous stage kernel: blocks [0,n1) = k1(c1), [n1,n1+n2) = k2(c2),
// rest = k3(c3). Roles within a launch are data-independent (different
// chunks); stream order provides inter-stage dependencies. Mixing read-heavy
// k1 with write-heavy k3 blends the CU read/write streams (R15/R17 counters:
// write 7.0 TB/s, k3 5.4, k1 ~4.0 — serial runs each with half the machine
// idle).
// ---------------------------------------------------------------------------
__global__ __launch_bounds__(256, 2) void gsc_stage(
    const float* __restrict__ U, const float* __restrict__ h,
    const float* __restrict__ W, float* __restrict__ hhp,
    __bf16* __restrict__ ohf, float* __restrict__ out,
    int n1, int c1, int n2, int c2, int c3)
{
    __shared__ float lds[2 * BUF];   // 48 KB (k1 dbuf; k2 borrows 8 KB)
    int bid = blockIdx.x;
    if (bid < n1) { k1_body(lds, U, h, hhp, bid, c1); return; }
    bid -= n1;
    if (bid < n2) { k2_body(lds, hhp, W, ohf, bid, c2); return; }
    bid -= n2;
    k3_body(U, ohf, out, bid, c3);
}

// ---------------------------------------------------------------------------
extern "C" void kernel_launch(void* const* d_in, const int* in_sizes, int n_in,
                              void* d_out, int out_size, void* d_ws, size_t ws_size,
                              hipStream_t stream) {
    const float* h = (const float*)d_in[0];   // [B*N, C]
    const float* U = (const float*)d_in[1];   // [B, N, M]
    const float* W = (const float*)d_in[2];   // [M, C, C]
    float* out = (float*)d_out;

    // hhp at the TAIL of d_out (rows b>=120): k3 touches that region only in
    // the final stage (c3=3), after k2(c3) consumed hhp. ohf in d_ws (2 MB).
    float*  hhp = out + ((size_t)BB * NN * CH - (size_t)BB * KSPLIT * MMCH);
    __bf16* ohf = (__bf16*)d_ws;

    // stage table: {n1, c1, n2, c2, n3, c3}
    const int S[6][6] = {
        {N1C, 0,   0, 0,   0, 0},
        {N1C, 1, N2C, 0,   0, 0},
        {N1C, 2, N2C, 1, N3C, 0},
        {N1C, 3, N2C, 2, N3C, 1},
        {  0, 0, N2C, 3, N3C, 2},
        {  0, 0,   0, 0, N3C, 3},
    };
    for (int s = 0; s < 6; ++s) {
        const int grid = S[s][0] + S[s][2] + S[s][4];
        gsc_stage<<<grid, 256, 0, stream>>>(U, h, W, hhp, ohf, out,
                                            S[s][0], S[s][1], S[s][2], S[s][3],
                                            S[s][5]);
    }
}